// Round 5
// baseline (583.508 us; speedup 1.0000x reference)
//
#include <hip/hip_runtime.h>
#include <hip/hip_bf16.h>

// Problem constants
#define BSZ 4
#define SEQ 2048
#define NH  16
#define DH  64
#define TOK (BSZ*SEQ)          // 8192 tokens
#define PROJC (NH*DH)          // 1024

typedef __bf16 bf16x8 __attribute__((ext_vector_type(8)));
typedef float  f32x4  __attribute__((ext_vector_type(4)));
typedef unsigned int uint4v __attribute__((ext_vector_type(4)));
typedef unsigned int uint2v __attribute__((ext_vector_type(2)));

__device__ inline unsigned short f2bf(float f) {
    __bf16 h = (__bf16)f;
    return __builtin_bit_cast(unsigned short, h);
}

__device__ inline bf16x8 ld8(const unsigned short* p) {
    return __builtin_bit_cast(bf16x8, *reinterpret_cast<const uint4v*>(p));
}

// ---------------- prep: f32 -> bf16 copies of q_origin / k_origin ----------
__global__ __launch_bounds__(256) void conv_kernel(const float* __restrict__ q,
                                                   const float* __restrict__ k,
                                                   unsigned short* __restrict__ qbf,
                                                   unsigned short* __restrict__ kbf) {
    int idx = blockIdx.x * 256 + threadIdx.x;       // 0 .. 524287
    if (blockIdx.y == 0) qbf[idx] = f2bf(q[idx]);
    else                 kbf[idx] = f2bf(k[idx]);
}

// ---------------- prep: W [64][cols] f32 -> WT [cols][64] bf16 -------------
__global__ __launch_bounds__(256) void wt_kernel(const float* __restrict__ W,
                                                 unsigned short* __restrict__ WT,
                                                 int cols) {
    int idx = blockIdx.x * 256 + threadIdx.x;
    int n = 64 * cols;
    if (idx >= n) return;
    int c = idx % cols, k = idx / cols;             // coalesced read over c
    WT[c * 64 + k] = f2bf(W[k * cols + c]);
}

// ---------------- mask bit-pack: int32 [b][q][k] -> uint64 bitrows ---------
__global__ __launch_bounds__(256) void maskpack_kernel(const int* __restrict__ mask,
                                                       unsigned long long* __restrict__ mbits) {
    size_t gid = (size_t)blockIdx.x * 256 + threadIdx.x;   // over 16M elements
    int lane = threadIdx.x & 63;
    unsigned long long bal = __ballot(mask[gid] != 0);
    if (lane == 0) mbits[gid >> 6] = bal;
}

// ---------------- projections: tokens x 64 @ 64 x 1024 ---------------------
__global__ __launch_bounds__(256) void proj_kernel(const unsigned short* __restrict__ qbf,
                                                   const unsigned short* __restrict__ kbf,
                                                   const unsigned short* __restrict__ WqT,
                                                   const unsigned short* __restrict__ WkT,
                                                   const unsigned short* __restrict__ WvT,
                                                   unsigned short* __restrict__ Qo,
                                                   unsigned short* __restrict__ Ko,
                                                   unsigned short* __restrict__ Vto) {
    int z = blockIdx.z;
    const unsigned short* A  = (z == 0) ? qbf : kbf;
    const unsigned short* WT = (z == 0) ? WqT : (z == 1) ? WkT : WvT;
    int tid = threadIdx.x, w = tid >> 6, lane = tid & 63;
    int l15 = lane & 15, l4 = lane >> 4;
    int r0 = blockIdx.x * 64 + w * 16;
    int c0 = blockIdx.y * 64;

    const unsigned short* ap = A + (r0 + l15) * 64 + l4 * 8;
    bf16x8 a0 = ld8(ap), a1 = ld8(ap + 32);

    for (int ct = 0; ct < 4; ++ct) {
        const unsigned short* wp = WT + (c0 + ct * 16 + l15) * 64 + l4 * 8;
        bf16x8 b0 = ld8(wp), b1 = ld8(wp + 32);
        f32x4 acc = {0.f, 0.f, 0.f, 0.f};
        acc = __builtin_amdgcn_mfma_f32_16x16x32_bf16(a0, b0, acc, 0, 0, 0);
        acc = __builtin_amdgcn_mfma_f32_16x16x32_bf16(a1, b1, acc, 0, 0, 0);
        for (int r = 0; r < 4; ++r) {
            int row = r0 + l4 * 4 + r;
            int col = c0 + ct * 16 + l15;
            int b = row >> 11, q = row & 2047;
            int h = col >> 6,  dd = col & 63;
            unsigned short val = f2bf(acc[r]);
            size_t bh = (size_t)(b * NH + h);
            if (z == 0)      Qo [(bh * SEQ + q) * 64 + dd] = val;
            else if (z == 1) Ko [(bh * SEQ + q) * 64 + dd] = val;
            else             Vto[(bh * 64 + dd) * SEQ + q] = val;
        }
    }
}

// ---------------- flash attention, swapped QK^T, static softmax max --------
// Flat grid 1024 (XCD-swizzled), 512 threads = 8 waves, 16 q rows per wave.
// 4 blocks/CU x 8 waves = 32 waves/CU (occupancy-max). No barriers: each
// wave owns a private LDS P-tile. S^T = mfma(K,Q): lane holds
// S[q=l15][k=l4*4+r] -> k-contiguous P per lane -> packed ds_write_b64.
// Static max m=0; fully-masked rows give ell==0 -> output 0 (nan_to_num).
__global__ __launch_bounds__(512, 8) void attn_kernel(const unsigned short* __restrict__ Q,
                                                      const unsigned short* __restrict__ K,
                                                      const unsigned short* __restrict__ Vt,
                                                      const unsigned long long* __restrict__ mbits,
                                                      unsigned short* __restrict__ O) {
    __shared__ __align__(16) unsigned short Pl[8][16][72];   // per-wave, +8 pad
    int tid = threadIdx.x, w = tid >> 6, lane = tid & 63;
    int l15 = lane & 15, l4 = lane >> 4;

    // XCD-aware swizzle: 8 consecutive bh per XCD (1024 % 8 == 0, bijective)
    int bid = blockIdx.x;
    int swz = (bid & 7) * 128 + (bid >> 3);
    int bh = swz >> 4;              // 0..63, bh-major within XCD chunk
    int qt = swz & 15;              // 0..15
    int b = bh >> 4;
    int qbase = qt * 128 + w * 16;

    const unsigned short* Qh = Q  + (size_t)bh * SEQ * 64;
    const unsigned short* Kh = K  + (size_t)bh * SEQ * 64;
    const unsigned short* Vh = Vt + (size_t)bh * 64 * SEQ;

    // per-lane mask row pointer (row = this lane's q = qbase + l15)
    const unsigned long long* mrow =
        mbits + ((size_t)b * SEQ + qbase + l15) * (SEQ / 64);

    const unsigned short* qp = Qh + (qbase + l15) * 64 + l4 * 8;
    bf16x8 qf0 = ld8(qp), qf1 = ld8(qp + 32);

    bf16x8 ones;
    #pragma unroll
    for (int i = 0; i < 8; ++i) ones[i] = (__bf16)1.0f;

    f32x4 o[4];
    #pragma unroll
    for (int i = 0; i < 4; ++i) o[i] = f32x4{0.f, 0.f, 0.f, 0.f};
    f32x4 ell = {0.f, 0.f, 0.f, 0.f};
    const float C = 0.125f * 1.44269504088896f;   // scale * log2(e)

    int shamt = l4 * 4;                            // lane's k sub-offset

    for (int kb = 0; kb < SEQ; kb += 64) {
        unsigned long long wb = mrow[kb >> 6];
        // ---- per 16-row k-tile: S^T = mfma(K,Q) -> mask -> exp2 -> packed LDS
        #pragma unroll
        for (int t = 0; t < 4; ++t) {
            const unsigned short* kp = Kh + ((size_t)(kb + t * 16 + l15)) * 64 + l4 * 8;
            bf16x8 k0 = ld8(kp), k1 = ld8(kp + 32);
            f32x4 z = {0.f, 0.f, 0.f, 0.f};
            z = __builtin_amdgcn_mfma_f32_16x16x32_bf16(k0, qf0, z, 0, 0, 0);
            z = __builtin_amdgcn_mfma_f32_16x16x32_bf16(k1, qf1, z, 0, 0, 0);
            unsigned bits = (unsigned)(wb >> (t * 16 + shamt)) & 0xFu;
            float p[4];
            #pragma unroll
            for (int r = 0; r < 4; ++r) {
                float e = __builtin_exp2f(z[r] * C);
                p[r] = (bits & (1u << r)) ? 0.f : e;
            }
            uint2v pk;
            pk.x = (unsigned)f2bf(p[0]) | ((unsigned)f2bf(p[1]) << 16);
            pk.y = (unsigned)f2bf(p[2]) | ((unsigned)f2bf(p[3]) << 16);
            *reinterpret_cast<uint2v*>(&Pl[w][l15][t * 16 + l4 * 4]) = pk;
        }
        // ---- A-frag of P, ell row-sum via ones-MFMA, then O += P V
        bf16x8 pa0 = ld8(&Pl[w][l15][l4 * 8]);
        bf16x8 pa1 = ld8(&Pl[w][l15][l4 * 8 + 32]);
        ell = __builtin_amdgcn_mfma_f32_16x16x32_bf16(pa0, ones, ell, 0, 0, 0);
        ell = __builtin_amdgcn_mfma_f32_16x16x32_bf16(pa1, ones, ell, 0, 0, 0);
        #pragma unroll
        for (int dt = 0; dt < 4; ++dt) {
            const unsigned short* vp = Vh + ((size_t)(dt * 16 + l15)) * SEQ + kb + l4 * 8;
            bf16x8 v0 = ld8(vp), v1 = ld8(vp + 32);
            o[dt] = __builtin_amdgcn_mfma_f32_16x16x32_bf16(pa0, v0, o[dt], 0, 0, 0);
            o[dt] = __builtin_amdgcn_mfma_f32_16x16x32_bf16(pa1, v1, o[dt], 0, 0, 0);
        }
    }
    // ---- normalize + store O[bh][q][64]; ell==0 (fully masked) -> 0
    float rcp[4];
    #pragma unroll
    for (int r = 0; r < 4; ++r)
        rcp[r] = (ell[r] == 0.f) ? 0.f : 1.f / ell[r];
    #pragma unroll
    for (int dt = 0; dt < 4; ++dt)
        #pragma unroll
        for (int r = 0; r < 4; ++r)
            O[((size_t)bh * SEQ + qbase + l4 * 4 + r) * 64 + dt * 16 + l15] =
                f2bf(o[dt][r] * rcp[r]);
}

// ---------------- FC + tanh: rows ordered (b, q, h) ------------------------
__global__ __launch_bounds__(256) void fc_kernel(const unsigned short* __restrict__ O,
                                                 const unsigned short* __restrict__ WfcT,
                                                 const float* __restrict__ bfc,
                                                 float* __restrict__ out) {
    int tid = threadIdx.x, w = tid >> 6, lane = tid & 63;
    int l15 = lane & 15, l4 = lane >> 4;
    int r0 = blockIdx.x * 64 + w * 16;

    int row = r0 + l15;
    int h = row & 15, t_ = row >> 4;
    int q = t_ & 2047, b = t_ >> 11;
    const unsigned short* op = O + (((size_t)(b * NH + h)) * SEQ + q) * 64 + l4 * 8;
    bf16x8 a0 = ld8(op), a1 = ld8(op + 32);

    for (int ct = 0; ct < 4; ++ct) {
        const unsigned short* wp = WfcT + (ct * 16 + l15) * 64 + l4 * 8;
        bf16x8 b0 = ld8(wp), b1 = ld8(wp + 32);
        f32x4 acc = {0.f, 0.f, 0.f, 0.f};
        acc = __builtin_amdgcn_mfma_f32_16x16x32_bf16(a0, b0, acc, 0, 0, 0);
        acc = __builtin_amdgcn_mfma_f32_16x16x32_bf16(a1, b1, acc, 0, 0, 0);
        float bias = bfc[ct * 16 + l15];
        for (int r = 0; r < 4; ++r)
            out[(size_t)(r0 + l4 * 4 + r) * 64 + ct * 16 + l15] =
                tanhf(acc[r] + bias);
    }
}

extern "C" void kernel_launch(void* const* d_in, const int* in_sizes, int n_in,
                              void* d_out, int out_size, void* d_ws, size_t ws_size,
                              hipStream_t stream) {
    const float* q_origin = (const float*)d_in[0];
    const float* k_origin = (const float*)d_in[1];
    const int*   mask     = (const int*)d_in[2];
    const float* Wq       = (const float*)d_in[3];
    const float* Wk       = (const float*)d_in[4];
    const float* Wv       = (const float*)d_in[5];
    const float* Wfc      = (const float*)d_in[6];
    const float* bfc      = (const float*)d_in[7];
    float* out = (float*)d_out;

    unsigned short* ws = (unsigned short*)d_ws;
    unsigned short* qbf  = ws;                 // 524288 (dead after proj)
    unsigned short* kbf  = qbf  + TOK * DH;    // 524288 (dead after proj)
    unsigned short* WqT  = kbf  + TOK * DH;    // 65536
    unsigned short* WkT  = WqT  + 64 * PROJC;
    unsigned short* WvT  = WkT  + 64 * PROJC;
    unsigned short* WfcT = WvT  + 64 * PROJC;  // 4096
    unsigned short* Qb   = WfcT + 64 * 64;     // 8388608 elems each
    unsigned short* Kb   = Qb   + (size_t)BSZ * NH * SEQ * DH;
    unsigned short* Vtb  = Kb   + (size_t)BSZ * NH * SEQ * DH;
    unsigned short* Ob   = Vtb  + (size_t)BSZ * NH * SEQ * DH;
    // mbits aliases qbf+kbf (2 MB exactly); packed AFTER proj consumes them
    unsigned long long* mbits = (unsigned long long*)d_ws;

    conv_kernel<<<dim3(2048, 2), 256, 0, stream>>>(q_origin, k_origin, qbf, kbf);
    wt_kernel<<<256, 256, 0, stream>>>(Wq, WqT, PROJC);
    wt_kernel<<<256, 256, 0, stream>>>(Wk, WkT, PROJC);
    wt_kernel<<<256, 256, 0, stream>>>(Wv, WvT, PROJC);
    wt_kernel<<<16, 256, 0, stream>>>(Wfc, WfcT, 64);
    proj_kernel<<<dim3(TOK / 64, PROJC / 64, 3), 256, 0, stream>>>(
        qbf, kbf, WqT, WkT, WvT, Qb, Kb, Vtb);
    maskpack_kernel<<<(size_t)BSZ * SEQ * SEQ / 256, 256, 0, stream>>>(mask, mbits);
    attn_kernel<<<1024, 512, 0, stream>>>(Qb, Kb, Vtb, mbits, Ob);
    fc_kernel<<<(size_t)BSZ * SEQ * NH / 64, 256, 0, stream>>>(Ob, WfcT, bfc, out);
}

// Round 6
// 236.740 us; speedup vs baseline: 2.4648x; 2.4648x over previous
//
#include <hip/hip_runtime.h>
#include <hip/hip_bf16.h>

// Problem constants
#define BSZ 4
#define SEQ 2048
#define NH  16
#define DH  64
#define TOK (BSZ*SEQ)          // 8192 tokens
#define PROJC (NH*DH)          // 1024

typedef __bf16 bf16x8 __attribute__((ext_vector_type(8)));
typedef float  f32x4  __attribute__((ext_vector_type(4)));
typedef unsigned int uint4v __attribute__((ext_vector_type(4)));
typedef unsigned int uint2v __attribute__((ext_vector_type(2)));

__device__ inline unsigned short f2bf(float f) {
    __bf16 h = (__bf16)f;
    return __builtin_bit_cast(unsigned short, h);
}

__device__ inline bf16x8 ld8(const unsigned short* p) {
    return __builtin_bit_cast(bf16x8, *reinterpret_cast<const uint4v*>(p));
}

// ---------------- prep: f32 -> bf16 copies of q_origin / k_origin ----------
__global__ __launch_bounds__(256) void conv_kernel(const float* __restrict__ q,
                                                   const float* __restrict__ k,
                                                   unsigned short* __restrict__ qbf,
                                                   unsigned short* __restrict__ kbf) {
    int idx = blockIdx.x * 256 + threadIdx.x;       // 0 .. 524287
    if (blockIdx.y == 0) qbf[idx] = f2bf(q[idx]);
    else                 kbf[idx] = f2bf(k[idx]);
}

// ---------------- prep: W [64][cols] f32 -> WT [cols][64] bf16 -------------
__global__ __launch_bounds__(256) void wt_kernel(const float* __restrict__ W,
                                                 unsigned short* __restrict__ WT,
                                                 int cols) {
    int idx = blockIdx.x * 256 + threadIdx.x;
    int n = 64 * cols;
    if (idx >= n) return;
    int c = idx % cols, k = idx / cols;             // coalesced read over c
    WT[c * 64 + k] = f2bf(W[k * cols + c]);
}

// ---------------- mask bit-pack: int32 [b][q][k] -> uint64 bitrows ---------
__global__ __launch_bounds__(256) void maskpack_kernel(const int* __restrict__ mask,
                                                       unsigned long long* __restrict__ mbits) {
    size_t gid = (size_t)blockIdx.x * 256 + threadIdx.x;   // over 16M elements
    int lane = threadIdx.x & 63;
    unsigned long long bal = __ballot(mask[gid] != 0);
    if (lane == 0) mbits[gid >> 6] = bal;
}

// ---------------- projections: tokens x 64 @ 64 x 1024 ---------------------
__global__ __launch_bounds__(256) void proj_kernel(const unsigned short* __restrict__ qbf,
                                                   const unsigned short* __restrict__ kbf,
                                                   const unsigned short* __restrict__ WqT,
                                                   const unsigned short* __restrict__ WkT,
                                                   const unsigned short* __restrict__ WvT,
                                                   unsigned short* __restrict__ Qo,
                                                   unsigned short* __restrict__ Ko,
                                                   unsigned short* __restrict__ Vto) {
    int z = blockIdx.z;
    const unsigned short* A  = (z == 0) ? qbf : kbf;
    const unsigned short* WT = (z == 0) ? WqT : (z == 1) ? WkT : WvT;
    int tid = threadIdx.x, w = tid >> 6, lane = tid & 63;
    int l15 = lane & 15, l4 = lane >> 4;
    int r0 = blockIdx.x * 64 + w * 16;
    int c0 = blockIdx.y * 64;

    const unsigned short* ap = A + (r0 + l15) * 64 + l4 * 8;
    bf16x8 a0 = ld8(ap), a1 = ld8(ap + 32);

    for (int ct = 0; ct < 4; ++ct) {
        const unsigned short* wp = WT + (c0 + ct * 16 + l15) * 64 + l4 * 8;
        bf16x8 b0 = ld8(wp), b1 = ld8(wp + 32);
        f32x4 acc = {0.f, 0.f, 0.f, 0.f};
        acc = __builtin_amdgcn_mfma_f32_16x16x32_bf16(a0, b0, acc, 0, 0, 0);
        acc = __builtin_amdgcn_mfma_f32_16x16x32_bf16(a1, b1, acc, 0, 0, 0);
        for (int r = 0; r < 4; ++r) {
            int row = r0 + l4 * 4 + r;
            int col = c0 + ct * 16 + l15;
            int b = row >> 11, q = row & 2047;
            int h = col >> 6,  dd = col & 63;
            unsigned short val = f2bf(acc[r]);
            size_t bh = (size_t)(b * NH + h);
            if (z == 0)      Qo [(bh * SEQ + q) * 64 + dd] = val;
            else if (z == 1) Ko [(bh * SEQ + q) * 64 + dd] = val;
            else             Vto[(bh * 64 + dd) * SEQ + q] = val;
        }
    }
}

// ---------------- flash attention: LDS-staged K/V, swapped QK^T ------------
// Grid 512 (XCD-swizzled), 512 threads = 8 waves, 32 q rows per wave (g=2),
// block covers 256 q rows of one bh. K/V tiles (64 x 64) double-buffered in
// LDS, staged cooperatively: loads issued at top of iter, ds_write at bottom
// -> HBM latency hidden under compute; one barrier per iter. 2 blocks/CU.
// Static softmax max m=0; fully-masked rows -> ell==0 -> 0 (nan_to_num).
__global__ __launch_bounds__(512, 4) void attn_kernel(const unsigned short* __restrict__ Q,
                                                      const unsigned short* __restrict__ K,
                                                      const unsigned short* __restrict__ Vt,
                                                      const unsigned long long* __restrict__ mbits,
                                                      unsigned short* __restrict__ O) {
    __shared__ __align__(16) unsigned short Ks[2][64][72];   // 18.4 KB
    __shared__ __align__(16) unsigned short Vs[2][64][72];   // 18.4 KB
    __shared__ __align__(16) unsigned short Pl[8][2][16][72]; // 36.9 KB, per-wave
    int tid = threadIdx.x, w = tid >> 6, lane = tid & 63;
    int l15 = lane & 15, l4 = lane >> 4;
    int srow = tid >> 3, scol = (tid & 7) * 8;     // staging: 16B per thread

    // XCD-aware swizzle: 512 % 8 == 0, bijective; 8 qtiles per bh
    int bid = blockIdx.x;
    int swz = (bid & 7) * 64 + (bid >> 3);
    int bh = swz >> 3;              // 0..63
    int qt = swz & 7;               // 0..7
    int b = bh >> 4;
    int qbase = qt * 256 + w * 32;

    const unsigned short* Qh = Q  + (size_t)bh * SEQ * 64;
    const unsigned short* Kh = K  + (size_t)bh * SEQ * 64;
    const unsigned short* Vh = Vt + (size_t)bh * 64 * SEQ;

    const unsigned long long* mrowg[2];
    #pragma unroll
    for (int g = 0; g < 2; ++g)
        mrowg[g] = mbits + ((size_t)b * SEQ + qbase + g * 16 + l15) * (SEQ / 64);

    bf16x8 qf[2][2];
    #pragma unroll
    for (int g = 0; g < 2; ++g) {
        const unsigned short* qp = Qh + (qbase + g * 16 + l15) * 64 + l4 * 8;
        qf[g][0] = ld8(qp);
        qf[g][1] = ld8(qp + 32);
    }

    bf16x8 ones;
    #pragma unroll
    for (int i = 0; i < 8; ++i) ones[i] = (__bf16)1.0f;

    f32x4 o[2][4];
    #pragma unroll
    for (int g = 0; g < 2; ++g)
        #pragma unroll
        for (int i = 0; i < 4; ++i) o[g][i] = f32x4{0.f, 0.f, 0.f, 0.f};
    f32x4 ell[2] = {{0.f, 0.f, 0.f, 0.f}, {0.f, 0.f, 0.f, 0.f}};
    const float C = 0.125f * 1.44269504088896f;   // scale * log2(e)
    int shamt = l4 * 4;

    // ---- prologue: stage tile kb=0 into buffer 0
    {
        uint4v k0 = *reinterpret_cast<const uint4v*>(Kh + (size_t)srow * 64 + scol);
        uint4v v0 = *reinterpret_cast<const uint4v*>(Vh + (size_t)srow * SEQ + scol);
        *reinterpret_cast<uint4v*>(&Ks[0][srow][scol]) = k0;
        *reinterpret_cast<uint4v*>(&Vs[0][srow][scol]) = v0;
    }
    __syncthreads();

    int cur = 0;
    for (int kb = 0; kb < SEQ; kb += 64) {
        // ---- issue next tile's loads (latency hidden under compute below)
        int nkb = (kb + 64) & (SEQ - 1);            // last iter wraps to 0 (harmless)
        uint4v knx = *reinterpret_cast<const uint4v*>(Kh + (size_t)(nkb + srow) * 64 + scol);
        uint4v vnx = *reinterpret_cast<const uint4v*>(Vh + (size_t)srow * SEQ + nkb + scol);

        unsigned long long wb[2];
        #pragma unroll
        for (int g = 0; g < 2; ++g) wb[g] = mrowg[g][kb >> 6];

        // ---- QK^T (swapped) from LDS K, exp2, pack P to per-wave LDS tile
        #pragma unroll
        for (int t = 0; t < 4; ++t) {
            bf16x8 k0 = ld8(&Ks[cur][t * 16 + l15][l4 * 8]);
            bf16x8 k1 = ld8(&Ks[cur][t * 16 + l15][l4 * 8 + 32]);
            #pragma unroll
            for (int g = 0; g < 2; ++g) {
                f32x4 z = {0.f, 0.f, 0.f, 0.f};
                z = __builtin_amdgcn_mfma_f32_16x16x32_bf16(k0, qf[g][0], z, 0, 0, 0);
                z = __builtin_amdgcn_mfma_f32_16x16x32_bf16(k1, qf[g][1], z, 0, 0, 0);
                unsigned bits = (unsigned)(wb[g] >> (t * 16 + shamt)) & 0xFu;
                float p[4];
                #pragma unroll
                for (int r = 0; r < 4; ++r) {
                    float e = __builtin_exp2f(z[r] * C);
                    p[r] = (bits & (1u << r)) ? 0.f : e;
                }
                uint2v pk;
                pk.x = (unsigned)f2bf(p[0]) | ((unsigned)f2bf(p[1]) << 16);
                pk.y = (unsigned)f2bf(p[2]) | ((unsigned)f2bf(p[3]) << 16);
                *reinterpret_cast<uint2v*>(&Pl[w][g][l15][t * 16 + l4 * 4]) = pk;
            }
        }
        // ---- A-frags of P, ell via ones-MFMA, O += P V (V from LDS)
        bf16x8 pa[2][2];
        #pragma unroll
        for (int g = 0; g < 2; ++g) {
            pa[g][0] = ld8(&Pl[w][g][l15][l4 * 8]);
            pa[g][1] = ld8(&Pl[w][g][l15][l4 * 8 + 32]);
            ell[g] = __builtin_amdgcn_mfma_f32_16x16x32_bf16(pa[g][0], ones, ell[g], 0, 0, 0);
            ell[g] = __builtin_amdgcn_mfma_f32_16x16x32_bf16(pa[g][1], ones, ell[g], 0, 0, 0);
        }
        #pragma unroll
        for (int dt = 0; dt < 4; ++dt) {
            bf16x8 v0 = ld8(&Vs[cur][dt * 16 + l15][l4 * 8]);
            bf16x8 v1 = ld8(&Vs[cur][dt * 16 + l15][l4 * 8 + 32]);
            #pragma unroll
            for (int g = 0; g < 2; ++g) {
                o[g][dt] = __builtin_amdgcn_mfma_f32_16x16x32_bf16(pa[g][0], v0, o[g][dt], 0, 0, 0);
                o[g][dt] = __builtin_amdgcn_mfma_f32_16x16x32_bf16(pa[g][1], v1, o[g][dt], 0, 0, 0);
            }
        }
        // ---- write next tile (waits vmcnt internally), one barrier per iter
        *reinterpret_cast<uint4v*>(&Ks[cur ^ 1][srow][scol]) = knx;
        *reinterpret_cast<uint4v*>(&Vs[cur ^ 1][srow][scol]) = vnx;
        __syncthreads();
        cur ^= 1;
    }
    // ---- normalize + store O[bh][q][64]; ell==0 (fully masked) -> 0
    #pragma unroll
    for (int g = 0; g < 2; ++g) {
        float rcp[4];
        #pragma unroll
        for (int r = 0; r < 4; ++r)
            rcp[r] = (ell[g][r] == 0.f) ? 0.f : 1.f / ell[g][r];
        #pragma unroll
        for (int dt = 0; dt < 4; ++dt)
            #pragma unroll
            for (int r = 0; r < 4; ++r)
                O[((size_t)bh * SEQ + qbase + g * 16 + l4 * 4 + r) * 64 + dt * 16 + l15] =
                    f2bf(o[g][dt][r] * rcp[r]);
    }
}

// ---------------- FC + tanh: rows ordered (b, q, h) ------------------------
__global__ __launch_bounds__(256) void fc_kernel(const unsigned short* __restrict__ O,
                                                 const unsigned short* __restrict__ WfcT,
                                                 const float* __restrict__ bfc,
                                                 float* __restrict__ out) {
    int tid = threadIdx.x, w = tid >> 6, lane = tid & 63;
    int l15 = lane & 15, l4 = lane >> 4;
    int r0 = blockIdx.x * 64 + w * 16;

    int row = r0 + l15;
    int h = row & 15, t_ = row >> 4;
    int q = t_ & 2047, b = t_ >> 11;
    const unsigned short* op = O + (((size_t)(b * NH + h)) * SEQ + q) * 64 + l4 * 8;
    bf16x8 a0 = ld8(op), a1 = ld8(op + 32);

    for (int ct = 0; ct < 4; ++ct) {
        const unsigned short* wp = WfcT + (ct * 16 + l15) * 64 + l4 * 8;
        bf16x8 b0 = ld8(wp), b1 = ld8(wp + 32);
        f32x4 acc = {0.f, 0.f, 0.f, 0.f};
        acc = __builtin_amdgcn_mfma_f32_16x16x32_bf16(a0, b0, acc, 0, 0, 0);
        acc = __builtin_amdgcn_mfma_f32_16x16x32_bf16(a1, b1, acc, 0, 0, 0);
        float bias = bfc[ct * 16 + l15];
        for (int r = 0; r < 4; ++r)
            out[(size_t)(r0 + l4 * 4 + r) * 64 + ct * 16 + l15] =
                tanhf(acc[r] + bias);
    }
}

extern "C" void kernel_launch(void* const* d_in, const int* in_sizes, int n_in,
                              void* d_out, int out_size, void* d_ws, size_t ws_size,
                              hipStream_t stream) {
    const float* q_origin = (const float*)d_in[0];
    const float* k_origin = (const float*)d_in[1];
    const int*   mask     = (const int*)d_in[2];
    const float* Wq       = (const float*)d_in[3];
    const float* Wk       = (const float*)d_in[4];
    const float* Wv       = (const float*)d_in[5];
    const float* Wfc      = (const float*)d_in[6];
    const float* bfc      = (const float*)d_in[7];
    float* out = (float*)d_out;

    unsigned short* ws = (unsigned short*)d_ws;
    unsigned short* qbf  = ws;                 // 524288 (dead after proj)
    unsigned short* kbf  = qbf  + TOK * DH;    // 524288 (dead after proj)
    unsigned short* WqT  = kbf  + TOK * DH;    // 65536
    unsigned short* WkT  = WqT  + 64 * PROJC;
    unsigned short* WvT  = WkT  + 64 * PROJC;
    unsigned short* WfcT = WvT  + 64 * PROJC;  // 4096
    unsigned short* Qb   = WfcT + 64 * 64;     // 8388608 elems each
    unsigned short* Kb   = Qb   + (size_t)BSZ * NH * SEQ * DH;
    unsigned short* Vtb  = Kb   + (size_t)BSZ * NH * SEQ * DH;
    unsigned short* Ob   = Vtb  + (size_t)BSZ * NH * SEQ * DH;
    // mbits aliases qbf+kbf (2 MB exactly); packed AFTER proj consumes them
    unsigned long long* mbits = (unsigned long long*)d_ws;

    conv_kernel<<<dim3(2048, 2), 256, 0, stream>>>(q_origin, k_origin, qbf, kbf);
    wt_kernel<<<256, 256, 0, stream>>>(Wq, WqT, PROJC);
    wt_kernel<<<256, 256, 0, stream>>>(Wk, WkT, PROJC);
    wt_kernel<<<256, 256, 0, stream>>>(Wv, WvT, PROJC);
    wt_kernel<<<16, 256, 0, stream>>>(Wfc, WfcT, 64);
    proj_kernel<<<dim3(TOK / 64, PROJC / 64, 3), 256, 0, stream>>>(
        qbf, kbf, WqT, WkT, WvT, Qb, Kb, Vtb);
    maskpack_kernel<<<(size_t)BSZ * SEQ * SEQ / 256, 256, 0, stream>>>(mask, mbits);
    attn_kernel<<<512, 512, 0, stream>>>(Qb, Kb, Vtb, mbits, Ob);
    fc_kernel<<<(size_t)BSZ * SEQ * NH / 64, 256, 0, stream>>>(Ob, WfcT, bfc, out);
}

// Round 7
// 220.643 us; speedup vs baseline: 2.6446x; 1.0730x over previous
//
#include <hip/hip_runtime.h>
#include <hip/hip_bf16.h>

// Problem constants
#define BSZ 4
#define SEQ 2048
#define NH  16
#define DH  64
#define TOK (BSZ*SEQ)          // 8192 tokens
#define PROJC (NH*DH)          // 1024

typedef __bf16 bf16x8 __attribute__((ext_vector_type(8)));
typedef float  f32x4  __attribute__((ext_vector_type(4)));
typedef unsigned int uint4v __attribute__((ext_vector_type(4)));
typedef unsigned int uint2v __attribute__((ext_vector_type(2)));

__device__ inline unsigned short f2bf(float f) {
    __bf16 h = (__bf16)f;
    return __builtin_bit_cast(unsigned short, h);
}

__device__ inline bf16x8 ld8(const unsigned short* p) {
    return __builtin_bit_cast(bf16x8, *reinterpret_cast<const uint4v*>(p));
}

// ---------------- fused prep: conv (f32->bf16) + 4x weight transpose -------
// blocks 0..2047: qbf ; 2048..4095: kbf ; 4096..4863: WqT/WkT/WvT ; 4864..4879: WfcT
__global__ __launch_bounds__(256) void prep_kernel(const float* __restrict__ q,
                                                   const float* __restrict__ k,
                                                   const float* __restrict__ Wq,
                                                   const float* __restrict__ Wk,
                                                   const float* __restrict__ Wv,
                                                   const float* __restrict__ Wfc,
                                                   unsigned short* __restrict__ qbf,
                                                   unsigned short* __restrict__ kbf,
                                                   unsigned short* __restrict__ WqT,
                                                   unsigned short* __restrict__ WkT,
                                                   unsigned short* __restrict__ WvT,
                                                   unsigned short* __restrict__ WfcT) {
    int bx = blockIdx.x;
    if (bx < 4096) {
        int idx = (bx & 2047) * 256 + threadIdx.x;
        if (bx < 2048) qbf[idx] = f2bf(q[idx]);
        else           kbf[idx] = f2bf(k[idx]);
        return;
    }
    bx -= 4096;
    const float* W; unsigned short* WT; int cols; int base;
    if      (bx < 256) { W = Wq;  WT = WqT;  cols = PROJC; base = bx; }
    else if (bx < 512) { W = Wk;  WT = WkT;  cols = PROJC; base = bx - 256; }
    else if (bx < 768) { W = Wv;  WT = WvT;  cols = PROJC; base = bx - 512; }
    else               { W = Wfc; WT = WfcT; cols = 64;    base = bx - 768; }
    int idx = base * 256 + threadIdx.x;
    int c = idx % cols, kk = idx / cols;
    WT[c * 64 + kk] = f2bf(W[kk * cols + c]);
}

// ---------------- mask bit-pack: int32 [b][q][k] -> uint64 bitrows ---------
__global__ __launch_bounds__(256) void maskpack_kernel(const int* __restrict__ mask,
                                                       unsigned long long* __restrict__ mbits) {
    size_t gid = (size_t)blockIdx.x * 256 + threadIdx.x;   // over 16M elements
    int lane = threadIdx.x & 63;
    unsigned long long bal = __ballot(mask[gid] != 0);
    if (lane == 0) mbits[gid >> 6] = bal;
}

// ---------------- projections: tokens x 64 @ 64 x 1024 ---------------------
// z=0: Q (swapped mfma -> lane holds 4 consecutive dd for one token)
// z=1: K (swapped, same)
// z=2: V -> Vt[bh][64][k] (unswapped -> lane holds 4 consecutive tokens)
// All epilogues: pack 4 bf16 -> one 8B store.
__global__ __launch_bounds__(256) void proj_kernel(const unsigned short* __restrict__ qbf,
                                                   const unsigned short* __restrict__ kbf,
                                                   const unsigned short* __restrict__ WqT,
                                                   const unsigned short* __restrict__ WkT,
                                                   const unsigned short* __restrict__ WvT,
                                                   unsigned short* __restrict__ Qo,
                                                   unsigned short* __restrict__ Ko,
                                                   unsigned short* __restrict__ Vto) {
    int z = blockIdx.z;
    const unsigned short* A  = (z == 0) ? qbf : kbf;
    const unsigned short* WT = (z == 0) ? WqT : (z == 1) ? WkT : WvT;
    int tid = threadIdx.x, w = tid >> 6, lane = tid & 63;
    int l15 = lane & 15, l4 = lane >> 4;
    int r0 = blockIdx.x * 64 + w * 16;
    int c0 = blockIdx.y * 64;
    int h = blockIdx.y;                 // c0/64
    int b = r0 >> 11;
    size_t bh = (size_t)(b * NH + h);

    const unsigned short* ap = A + (r0 + l15) * 64 + l4 * 8;
    bf16x8 a0 = ld8(ap), a1 = ld8(ap + 32);

    for (int ct = 0; ct < 4; ++ct) {
        const unsigned short* wp = WT + (c0 + ct * 16 + l15) * 64 + l4 * 8;
        bf16x8 b0 = ld8(wp), b1 = ld8(wp + 32);
        f32x4 acc = {0.f, 0.f, 0.f, 0.f};
        if (z == 2) {
            acc = __builtin_amdgcn_mfma_f32_16x16x32_bf16(a0, b0, acc, 0, 0, 0);
            acc = __builtin_amdgcn_mfma_f32_16x16x32_bf16(a1, b1, acc, 0, 0, 0);
        } else {
            acc = __builtin_amdgcn_mfma_f32_16x16x32_bf16(b0, a0, acc, 0, 0, 0);
            acc = __builtin_amdgcn_mfma_f32_16x16x32_bf16(b1, a1, acc, 0, 0, 0);
        }
        uint2v pk;
        pk.x = (unsigned)f2bf(acc[0]) | ((unsigned)f2bf(acc[1]) << 16);
        pk.y = (unsigned)f2bf(acc[2]) | ((unsigned)f2bf(acc[3]) << 16);
        if (z == 2) {
            // lane: token q0..q0+3, col dd = ct*16+l15
            int dd = ct * 16 + l15;
            int q0 = (r0 + l4 * 4) & 2047;
            *reinterpret_cast<uint2v*>(Vto + (bh * 64 + dd) * SEQ + q0) = pk;
        } else {
            // lane: token q, dd = ct*16 + l4*4 .. +3
            int qq = (r0 + l15) & 2047;
            unsigned short* dst = (z == 0) ? Qo : Ko;
            *reinterpret_cast<uint2v*>(dst + (bh * SEQ + qq) * 64 + ct * 16 + l4 * 4) = pk;
        }
    }
}

// ---------------- flash attention: LDS-staged K/V, swapped QK^T ------------
// Grid 512 (XCD-swizzled), 512 threads = 8 waves, 32 q rows per wave (g=2),
// block covers 256 q rows of one bh. K/V tiles double-buffered in LDS,
// staged cooperatively (loads at top of iter, ds_write at bottom). Mask is
// folded into the exp2 argument as a 0/-inf bias (exp2(-inf)=0 exactly).
// Static softmax max m=0; fully-masked rows -> ell==0 -> 0 (nan_to_num).
__global__ __launch_bounds__(512, 4) void attn_kernel(const unsigned short* __restrict__ Q,
                                                      const unsigned short* __restrict__ K,
                                                      const unsigned short* __restrict__ Vt,
                                                      const unsigned long long* __restrict__ mbits,
                                                      unsigned short* __restrict__ O) {
    __shared__ __align__(16) unsigned short Ks[2][64][72];
    __shared__ __align__(16) unsigned short Vs[2][64][72];
    __shared__ __align__(16) unsigned short Pl[8][2][16][72];
    int tid = threadIdx.x, w = tid >> 6, lane = tid & 63;
    int l15 = lane & 15, l4 = lane >> 4;
    int srow = tid >> 3, scol = (tid & 7) * 8;     // staging: 16B per thread

    // XCD-aware swizzle: 512 % 8 == 0, bijective; 8 qtiles per bh
    int bid = blockIdx.x;
    int swz = (bid & 7) * 64 + (bid >> 3);
    int bh = swz >> 3;              // 0..63
    int qt = swz & 7;               // 0..7
    int b = bh >> 4;
    int qbase = qt * 256 + w * 32;

    const unsigned short* Qh = Q  + (size_t)bh * SEQ * 64;
    const unsigned short* Kh = K  + (size_t)bh * SEQ * 64;
    const unsigned short* Vh = Vt + (size_t)bh * 64 * SEQ;

    const unsigned long long* mrowg[2];
    #pragma unroll
    for (int g = 0; g < 2; ++g)
        mrowg[g] = mbits + ((size_t)b * SEQ + qbase + g * 16 + l15) * (SEQ / 64);

    bf16x8 qf[2][2];
    #pragma unroll
    for (int g = 0; g < 2; ++g) {
        const unsigned short* qp = Qh + (qbase + g * 16 + l15) * 64 + l4 * 8;
        qf[g][0] = ld8(qp);
        qf[g][1] = ld8(qp + 32);
    }

    bf16x8 ones;
    #pragma unroll
    for (int i = 0; i < 8; ++i) ones[i] = (__bf16)1.0f;

    f32x4 o[2][4];
    #pragma unroll
    for (int g = 0; g < 2; ++g)
        #pragma unroll
        for (int i = 0; i < 4; ++i) o[g][i] = f32x4{0.f, 0.f, 0.f, 0.f};
    f32x4 ell[2] = {{0.f, 0.f, 0.f, 0.f}, {0.f, 0.f, 0.f, 0.f}};
    const float C = 0.125f * 1.44269504088896f;   // scale * log2(e)
    int shamt = l4 * 4;

    // ---- prologue: stage tile kb=0 into buffer 0
    {
        uint4v k0 = *reinterpret_cast<const uint4v*>(Kh + (size_t)srow * 64 + scol);
        uint4v v0 = *reinterpret_cast<const uint4v*>(Vh + (size_t)srow * SEQ + scol);
        *reinterpret_cast<uint4v*>(&Ks[0][srow][scol]) = k0;
        *reinterpret_cast<uint4v*>(&Vs[0][srow][scol]) = v0;
    }
    __syncthreads();

    int cur = 0;
    for (int kb = 0; kb < SEQ; kb += 64) {
        // ---- issue next tile's loads (latency hidden under compute below)
        int nkb = (kb + 64) & (SEQ - 1);
        uint4v knx = *reinterpret_cast<const uint4v*>(Kh + (size_t)(nkb + srow) * 64 + scol);
        uint4v vnx = *reinterpret_cast<const uint4v*>(Vh + (size_t)srow * SEQ + nkb + scol);

        unsigned long long wb[2];
        #pragma unroll
        for (int g = 0; g < 2; ++g) wb[g] = mrowg[g][kb >> 6];

        // ---- QK^T (swapped) from LDS K; mask folded as 0/-inf exp2 bias
        #pragma unroll
        for (int t = 0; t < 4; ++t) {
            bf16x8 k0 = ld8(&Ks[cur][t * 16 + l15][l4 * 8]);
            bf16x8 k1 = ld8(&Ks[cur][t * 16 + l15][l4 * 8 + 32]);
            #pragma unroll
            for (int g = 0; g < 2; ++g) {
                f32x4 z = {0.f, 0.f, 0.f, 0.f};
                z = __builtin_amdgcn_mfma_f32_16x16x32_bf16(k0, qf[g][0], z, 0, 0, 0);
                z = __builtin_amdgcn_mfma_f32_16x16x32_bf16(k1, qf[g][1], z, 0, 0, 0);
                unsigned bits = (unsigned)(wb[g] >> (t * 16 + shamt)) & 0xFu;
                float e[4];
                #pragma unroll
                for (int r = 0; r < 4; ++r) {
                    int sx = (int)(bits << (31 - r)) >> 31;   // -(bit r): 0 or -1
                    float bias = __builtin_bit_cast(float, (unsigned)sx & 0xFF800000u);
                    e[r] = __builtin_exp2f(__builtin_fmaf(z[r], C, bias));
                }
                uint2v pk;
                pk.x = (unsigned)f2bf(e[0]) | ((unsigned)f2bf(e[1]) << 16);
                pk.y = (unsigned)f2bf(e[2]) | ((unsigned)f2bf(e[3]) << 16);
                *reinterpret_cast<uint2v*>(&Pl[w][g][l15][t * 16 + l4 * 4]) = pk;
            }
        }
        // ---- A-frags of P, ell via ones-MFMA, O += P V (V from LDS)
        bf16x8 pa[2][2];
        #pragma unroll
        for (int g = 0; g < 2; ++g) {
            pa[g][0] = ld8(&Pl[w][g][l15][l4 * 8]);
            pa[g][1] = ld8(&Pl[w][g][l15][l4 * 8 + 32]);
            ell[g] = __builtin_amdgcn_mfma_f32_16x16x32_bf16(pa[g][0], ones, ell[g], 0, 0, 0);
            ell[g] = __builtin_amdgcn_mfma_f32_16x16x32_bf16(pa[g][1], ones, ell[g], 0, 0, 0);
        }
        __builtin_amdgcn_s_setprio(1);
        #pragma unroll
        for (int dt = 0; dt < 4; ++dt) {
            bf16x8 v0 = ld8(&Vs[cur][dt * 16 + l15][l4 * 8]);
            bf16x8 v1 = ld8(&Vs[cur][dt * 16 + l15][l4 * 8 + 32]);
            #pragma unroll
            for (int g = 0; g < 2; ++g) {
                o[g][dt] = __builtin_amdgcn_mfma_f32_16x16x32_bf16(pa[g][0], v0, o[g][dt], 0, 0, 0);
                o[g][dt] = __builtin_amdgcn_mfma_f32_16x16x32_bf16(pa[g][1], v1, o[g][dt], 0, 0, 0);
            }
        }
        __builtin_amdgcn_s_setprio(0);
        // ---- write next tile, one barrier per iter
        *reinterpret_cast<uint4v*>(&Ks[cur ^ 1][srow][scol]) = knx;
        *reinterpret_cast<uint4v*>(&Vs[cur ^ 1][srow][scol]) = vnx;
        __syncthreads();
        cur ^= 1;
    }
    // ---- normalize + store O[bh][q][64]; ell==0 (fully masked) -> 0
    #pragma unroll
    for (int g = 0; g < 2; ++g) {
        float rcp[4];
        #pragma unroll
        for (int r = 0; r < 4; ++r)
            rcp[r] = (ell[g][r] == 0.f) ? 0.f : 1.f / ell[g][r];
        #pragma unroll
        for (int dt = 0; dt < 4; ++dt)
            #pragma unroll
            for (int r = 0; r < 4; ++r)
                O[((size_t)bh * SEQ + qbase + g * 16 + l4 * 4 + r) * 64 + dt * 16 + l15] =
                    f2bf(o[g][dt][r] * rcp[r]);
    }
}

// ---------------- FC + tanh: rows ordered (b, q, h) ------------------------
__global__ __launch_bounds__(256) void fc_kernel(const unsigned short* __restrict__ O,
                                                 const unsigned short* __restrict__ WfcT,
                                                 const float* __restrict__ bfc,
                                                 float* __restrict__ out) {
    int tid = threadIdx.x, w = tid >> 6, lane = tid & 63;
    int l15 = lane & 15, l4 = lane >> 4;
    int r0 = blockIdx.x * 64 + w * 16;

    int row = r0 + l15;
    int h = row & 15, t_ = row >> 4;
    int q = t_ & 2047, b = t_ >> 11;
    const unsigned short* op = O + (((size_t)(b * NH + h)) * SEQ + q) * 64 + l4 * 8;
    bf16x8 a0 = ld8(op), a1 = ld8(op + 32);

    for (int ct = 0; ct < 4; ++ct) {
        const unsigned short* wp = WfcT + (ct * 16 + l15) * 64 + l4 * 8;
        bf16x8 b0 = ld8(wp), b1 = ld8(wp + 32);
        f32x4 acc = {0.f, 0.f, 0.f, 0.f};
        acc = __builtin_amdgcn_mfma_f32_16x16x32_bf16(a0, b0, acc, 0, 0, 0);
        acc = __builtin_amdgcn_mfma_f32_16x16x32_bf16(a1, b1, acc, 0, 0, 0);
        float bias = bfc[ct * 16 + l15];
        for (int r = 0; r < 4; ++r)
            out[(size_t)(r0 + l4 * 4 + r) * 64 + ct * 16 + l15] =
                tanhf(acc[r] + bias);
    }
}

extern "C" void kernel_launch(void* const* d_in, const int* in_sizes, int n_in,
                              void* d_out, int out_size, void* d_ws, size_t ws_size,
                              hipStream_t stream) {
    const float* q_origin = (const float*)d_in[0];
    const float* k_origin = (const float*)d_in[1];
    const int*   mask     = (const int*)d_in[2];
    const float* Wq       = (const float*)d_in[3];
    const float* Wk       = (const float*)d_in[4];
    const float* Wv       = (const float*)d_in[5];
    const float* Wfc      = (const float*)d_in[6];
    const float* bfc      = (const float*)d_in[7];
    float* out = (float*)d_out;

    unsigned short* ws = (unsigned short*)d_ws;
    unsigned short* qbf  = ws;                 // 524288 (dead after proj)
    unsigned short* kbf  = qbf  + TOK * DH;    // 524288 (dead after proj)
    unsigned short* WqT  = kbf  + TOK * DH;    // 65536
    unsigned short* WkT  = WqT  + 64 * PROJC;
    unsigned short* WvT  = WkT  + 64 * PROJC;
    unsigned short* WfcT = WvT  + 64 * PROJC;  // 4096
    unsigned short* Qb   = WfcT + 64 * 64;     // 8388608 elems each
    unsigned short* Kb   = Qb   + (size_t)BSZ * NH * SEQ * DH;
    unsigned short* Vtb  = Kb   + (size_t)BSZ * NH * SEQ * DH;
    unsigned short* Ob   = Vtb  + (size_t)BSZ * NH * SEQ * DH;
    // mbits aliases qbf+kbf (2 MB exactly); packed AFTER proj consumes them
    unsigned long long* mbits = (unsigned long long*)d_ws;

    prep_kernel<<<4880, 256, 0, stream>>>(q_origin, k_origin, Wq, Wk, Wv, Wfc,
                                          qbf, kbf, WqT, WkT, WvT, WfcT);
    proj_kernel<<<dim3(TOK / 64, PROJC / 64, 3), 256, 0, stream>>>(
        qbf, kbf, WqT, WkT, WvT, Qb, Kb, Vtb);
    maskpack_kernel<<<(size_t)BSZ * SEQ * SEQ / 256, 256, 0, stream>>>(mask, mbits);
    attn_kernel<<<512, 512, 0, stream>>>(Qb, Kb, Vtb, mbits, Ob);
    fc_kernel<<<(size_t)BSZ * SEQ * NH / 64, 256, 0, stream>>>(Ob, WfcT, bfc, out);
}

// Round 8
// 209.845 us; speedup vs baseline: 2.7807x; 1.0515x over previous
//
#include <hip/hip_runtime.h>
#include <hip/hip_bf16.h>

// Problem constants
#define BSZ 4
#define SEQ 2048
#define NH  16
#define DH  64
#define TOK (BSZ*SEQ)          // 8192 tokens
#define PROJC (NH*DH)          // 1024

typedef __bf16 bf16x8 __attribute__((ext_vector_type(8)));
typedef float  f32x4  __attribute__((ext_vector_type(4)));
typedef float  f32x16 __attribute__((ext_vector_type(16)));
typedef unsigned int uint4v __attribute__((ext_vector_type(4)));
typedef unsigned int uint2v __attribute__((ext_vector_type(2)));

__device__ inline unsigned short f2bf(float f) {
    __bf16 h = (__bf16)f;
    return __builtin_bit_cast(unsigned short, h);
}

__device__ inline bf16x8 ld8(const unsigned short* p) {
    return __builtin_bit_cast(bf16x8, *reinterpret_cast<const uint4v*>(p));
}

// async global -> LDS, 16B per lane; LDS dest = wave-uniform base + lane*16
__device__ inline void gload16(const unsigned short* g, unsigned short* l) {
    __builtin_amdgcn_global_load_lds(
        (__attribute__((address_space(1))) void*)g,
        (__attribute__((address_space(3))) void*)l, 16, 0, 0);
}

// ---------------- fused prep: conv (f32->bf16) + 4x weight transpose -------
__global__ __launch_bounds__(256) void prep_kernel(const float* __restrict__ q,
                                                   const float* __restrict__ k,
                                                   const float* __restrict__ Wq,
                                                   const float* __restrict__ Wk,
                                                   const float* __restrict__ Wv,
                                                   const float* __restrict__ Wfc,
                                                   unsigned short* __restrict__ qbf,
                                                   unsigned short* __restrict__ kbf,
                                                   unsigned short* __restrict__ WqT,
                                                   unsigned short* __restrict__ WkT,
                                                   unsigned short* __restrict__ WvT,
                                                   unsigned short* __restrict__ WfcT) {
    int bx = blockIdx.x;
    if (bx < 4096) {
        int idx = (bx & 2047) * 256 + threadIdx.x;
        if (bx < 2048) qbf[idx] = f2bf(q[idx]);
        else           kbf[idx] = f2bf(k[idx]);
        return;
    }
    bx -= 4096;
    const float* W; unsigned short* WT; int cols; int base;
    if      (bx < 256) { W = Wq;  WT = WqT;  cols = PROJC; base = bx; }
    else if (bx < 512) { W = Wk;  WT = WkT;  cols = PROJC; base = bx - 256; }
    else if (bx < 768) { W = Wv;  WT = WvT;  cols = PROJC; base = bx - 512; }
    else               { W = Wfc; WT = WfcT; cols = 64;    base = bx - 768; }
    int idx = base * 256 + threadIdx.x;
    int c = idx % cols, kk = idx / cols;
    WT[c * 64 + kk] = f2bf(W[kk * cols + c]);
}

// ---------------- mask bit-pack: int32 [b][q][k] -> uint64 bitrows ---------
__global__ __launch_bounds__(256) void maskpack_kernel(const int* __restrict__ mask,
                                                       unsigned long long* __restrict__ mbits) {
    size_t gid = (size_t)blockIdx.x * 256 + threadIdx.x;
    int lane = threadIdx.x & 63;
    unsigned long long bal = __ballot(mask[gid] != 0);
    if (lane == 0) mbits[gid >> 6] = bal;
}

// ---------------- projections: tokens x 64 @ 64 x 1024 ---------------------
__global__ __launch_bounds__(256) void proj_kernel(const unsigned short* __restrict__ qbf,
                                                   const unsigned short* __restrict__ kbf,
                                                   const unsigned short* __restrict__ WqT,
                                                   const unsigned short* __restrict__ WkT,
                                                   const unsigned short* __restrict__ WvT,
                                                   unsigned short* __restrict__ Qo,
                                                   unsigned short* __restrict__ Ko,
                                                   unsigned short* __restrict__ Vto) {
    int z = blockIdx.z;
    const unsigned short* A  = (z == 0) ? qbf : kbf;
    const unsigned short* WT = (z == 0) ? WqT : (z == 1) ? WkT : WvT;
    int tid = threadIdx.x, w = tid >> 6, lane = tid & 63;
    int l15 = lane & 15, l4 = lane >> 4;
    int r0 = blockIdx.x * 64 + w * 16;
    int c0 = blockIdx.y * 64;
    int h = blockIdx.y;
    int b = r0 >> 11;
    size_t bh = (size_t)(b * NH + h);

    const unsigned short* ap = A + (r0 + l15) * 64 + l4 * 8;
    bf16x8 a0 = ld8(ap), a1 = ld8(ap + 32);

    for (int ct = 0; ct < 4; ++ct) {
        const unsigned short* wp = WT + (c0 + ct * 16 + l15) * 64 + l4 * 8;
        bf16x8 b0 = ld8(wp), b1 = ld8(wp + 32);
        f32x4 acc = {0.f, 0.f, 0.f, 0.f};
        if (z == 2) {
            acc = __builtin_amdgcn_mfma_f32_16x16x32_bf16(a0, b0, acc, 0, 0, 0);
            acc = __builtin_amdgcn_mfma_f32_16x16x32_bf16(a1, b1, acc, 0, 0, 0);
        } else {
            acc = __builtin_amdgcn_mfma_f32_16x16x32_bf16(b0, a0, acc, 0, 0, 0);
            acc = __builtin_amdgcn_mfma_f32_16x16x32_bf16(b1, a1, acc, 0, 0, 0);
        }
        uint2v pk;
        pk.x = (unsigned)f2bf(acc[0]) | ((unsigned)f2bf(acc[1]) << 16);
        pk.y = (unsigned)f2bf(acc[2]) | ((unsigned)f2bf(acc[3]) << 16);
        if (z == 2) {
            int dd = ct * 16 + l15;
            int q0 = (r0 + l4 * 4) & 2047;
            *reinterpret_cast<uint2v*>(Vto + (bh * 64 + dd) * SEQ + q0) = pk;
        } else {
            int qq = (r0 + l15) & 2047;
            unsigned short* dst = (z == 0) ? Qo : Ko;
            *reinterpret_cast<uint2v*>(dst + (bh * SEQ + qq) * 64 + ct * 16 + l4 * 4) = pk;
        }
    }
}

// ---------------- flash attention: 32x32 MFMA, P fully in-register ---------
// Grid 1024 (XCD-swizzled), 256 threads = 4 waves, 32 q rows per wave.
// K/V tiles [64][64] double-buffered in LDS via global_load_lds (linear dest,
// XOR-16B-swizzled source; reads apply the same XOR). Swapped QK^T: lane
// (q=lane&31, hi) holds S[q][k=(reg&3)+8*(reg>>2)+4*hi]. PV k-slices chosen
// as the union of the two half-wave k-sets, so the PV A-frag is the lane's
// own 4 packed words (no cross-lane, no P LDS). ell via ones-MFMA lands in
// O's D-layout. Static max m=0; fully-masked rows -> ell==0 -> 0.
__global__ __launch_bounds__(256, 4) void attn_kernel(const unsigned short* __restrict__ Q,
                                                      const unsigned short* __restrict__ K,
                                                      const unsigned short* __restrict__ Vt,
                                                      const unsigned long long* __restrict__ mbits,
                                                      unsigned short* __restrict__ O) {
    __shared__ __align__(16) unsigned short Ks[2][64 * 64];   // 16 KB
    __shared__ __align__(16) unsigned short Vs[2][64 * 64];   // 16 KB
    int tid = threadIdx.x, w = tid >> 6, lane = tid & 63;
    int l31 = lane & 31, hi = lane >> 5;
    int hi4 = hi * 4;

    // XCD-aware swizzle: 1024 % 8 == 0, bijective
    int bid = blockIdx.x;
    int swz = (bid & 7) * 128 + (bid >> 3);
    int bh = swz >> 4;              // 0..63
    int qt = swz & 15;              // 0..15
    int b = bh >> 4;
    int qbase = qt * 128 + w * 32;

    const unsigned short* Qh = Q  + (size_t)bh * SEQ * 64;
    const unsigned short* Kh = K  + (size_t)bh * SEQ * 64;
    const unsigned short* Vh = Vt + (size_t)bh * 64 * SEQ;
    const unsigned long long* mrow =
        mbits + ((size_t)b * SEQ + qbase + l31) * (SEQ / 64);

    // staging geometry: chunk idx = w*64 + lane (+256), row = idx>>3, col16 = idx&7
    int row1 = (w << 3) + (lane >> 3);          // 0..31
    int row2 = row1 + 32;
    int sc1 = (lane & 7) ^ (row1 & 7);          // source chunk (XOR involution)
    unsigned short* Kd0 = &Ks[0][0] + w * 512;
    unsigned short* Vd0 = &Vs[0][0] + w * 512;
    unsigned short* Kd1 = &Ks[1][0] + w * 512;
    unsigned short* Vd1 = &Vs[1][0] + w * 512;

    // Q B-frags: lane holds Q[qbase+l31][s*16 + hi*8 + j]
    bf16x8 qf[4];
    #pragma unroll
    for (int s = 0; s < 4; ++s)
        qf[s] = ld8(Qh + (size_t)(qbase + l31) * 64 + s * 16 + hi * 8);

    bf16x8 ones;
    #pragma unroll
    for (int i = 0; i < 8; ++i) ones[i] = (__bf16)1.0f;

    f32x16 o0 = {0.f,0.f,0.f,0.f,0.f,0.f,0.f,0.f,0.f,0.f,0.f,0.f,0.f,0.f,0.f,0.f};
    f32x16 o1 = o0;
    f32x16 ellD = o0;
    const float C = 0.125f * 1.44269504088896f;   // scale * log2(e)

    // prologue: stage kb=0 into buffer 0
    gload16(Kh + (size_t)row1 * 64 + sc1 * 8, Kd0);
    gload16(Kh + (size_t)row2 * 64 + sc1 * 8, Kd0 + 2048);
    gload16(Vh + (size_t)row1 * SEQ + sc1 * 8, Vd0);
    gload16(Vh + (size_t)row2 * SEQ + sc1 * 8, Vd0 + 2048);
    __syncthreads();

    int cur = 0;
    for (int kb = 0; kb < SEQ; kb += 64) {
        // ---- stage next tile (async DMA, in flight across compute)
        if (kb + 64 < SEQ) {
            int nkb = kb + 64;
            unsigned short* Kd = cur ? Kd0 : Kd1;
            unsigned short* Vd = cur ? Vd0 : Vd1;
            gload16(Kh + (size_t)(nkb + row1) * 64 + sc1 * 8, Kd);
            gload16(Kh + (size_t)(nkb + row2) * 64 + sc1 * 8, Kd + 2048);
            gload16(Vh + (size_t)row1 * SEQ + nkb + sc1 * 8, Vd);
            gload16(Vh + (size_t)row2 * SEQ + nkb + sc1 * 8, Vd + 2048);
        }
        unsigned long long wb = mrow[kb >> 6];
        const unsigned short* Kc = &Ks[cur][0];
        const unsigned short* Vc = &Vs[cur][0];

        #pragma unroll
        for (int kt = 0; kt < 2; ++kt) {
            // ---- QK^T (swapped): z[reg] = S[q=l31][k=kt*32+(reg&3)+8*(reg>>2)+4hi]
            f32x16 z = {0.f,0.f,0.f,0.f,0.f,0.f,0.f,0.f,0.f,0.f,0.f,0.f,0.f,0.f,0.f,0.f};
            int krow = kt * 32 + l31;
            #pragma unroll
            for (int s = 0; s < 4; ++s) {
                const unsigned short* kp =
                    Kc + krow * 64 + ((((s << 1) + hi) ^ (krow & 7)) << 3);
                z = __builtin_amdgcn_mfma_f32_32x32x16_bf16(ld8(kp), qf[s], z, 0, 0, 0);
            }
            // ---- mask (0/-inf bias) + exp2 + cvt_pk -> 8 words of P (bf16 x2)
            unsigned wpk[8];
            #pragma unroll
            for (int rq = 0; rq < 4; ++rq) {
                unsigned nib = (unsigned)(wb >> (kt * 32 + rq * 8 + hi4)) & 0xFu;
                #pragma unroll
                for (int rr = 0; rr < 2; ++rr) {
                    int s0 = (int)(nib << (31 - 2 * rr)) >> 31;
                    int s1 = (int)(nib << (30 - 2 * rr)) >> 31;
                    float b0 = __builtin_bit_cast(float, (unsigned)s0 & 0xFF800000u);
                    float b1 = __builtin_bit_cast(float, (unsigned)s1 & 0xFF800000u);
                    float e0 = __builtin_exp2f(__builtin_fmaf(z[rq * 4 + 2 * rr], C, b0));
                    float e1 = __builtin_exp2f(__builtin_fmaf(z[rq * 4 + 2 * rr + 1], C, b1));
                    wpk[rq * 2 + rr] = (unsigned)f2bf(e0) | ((unsigned)f2bf(e1) << 16);
                }
            }
            // ---- ell + PV: A-frag = own words (k-subset trick), V matches
            __builtin_amdgcn_s_setprio(1);
            #pragma unroll
            for (int sl = 0; sl < 2; ++sl) {
                uint4v aw = {wpk[sl * 4 + 0], wpk[sl * 4 + 1],
                             wpk[sl * 4 + 2], wpk[sl * 4 + 3]};
                bf16x8 af = __builtin_bit_cast(bf16x8, aw);
                ellD = __builtin_amdgcn_mfma_f32_32x32x16_bf16(af, ones, ellD, 0, 0, 0);
                int n = kt * 2 + sl;            // k-subtile of 16 within kb
                {   // dtile 0
                    int vrow = l31;
                    int c0i = ((2 * n) ^ (vrow & 7)) << 3;
                    int c1i = ((2 * n + 1) ^ (vrow & 7)) << 3;
                    uint2v lo = *reinterpret_cast<const uint2v*>(Vc + vrow * 64 + c0i + hi4);
                    uint2v hh = *reinterpret_cast<const uint2v*>(Vc + vrow * 64 + c1i + hi4);
                    uint4v vw = {lo.x, lo.y, hh.x, hh.y};
                    o0 = __builtin_amdgcn_mfma_f32_32x32x16_bf16(
                        af, __builtin_bit_cast(bf16x8, vw), o0, 0, 0, 0);
                }
                {   // dtile 1
                    int vrow = 32 + l31;
                    int c0i = ((2 * n) ^ (vrow & 7)) << 3;
                    int c1i = ((2 * n + 1) ^ (vrow & 7)) << 3;
                    uint2v lo = *reinterpret_cast<const uint2v*>(Vc + vrow * 64 + c0i + hi4);
                    uint2v hh = *reinterpret_cast<const uint2v*>(Vc + vrow * 64 + c1i + hi4);
                    uint4v vw = {lo.x, lo.y, hh.x, hh.y};
                    o1 = __builtin_amdgcn_mfma_f32_32x32x16_bf16(
                        af, __builtin_bit_cast(bf16x8, vw), o1, 0, 0, 0);
                }
            }
            __builtin_amdgcn_s_setprio(0);
        }
        __syncthreads();
        cur ^= 1;
    }
    // ---- normalize + store; lane holds O[q=(reg&3)+8*(reg>>2)+4hi][d=dt*32+l31]
    #pragma unroll
    for (int reg = 0; reg < 16; ++reg) {
        float l = ellD[reg];
        float rcp = (l == 0.f) ? 0.f : 1.f / l;
        int ql = (reg & 3) + 8 * (reg >> 2) + hi4;
        size_t base = ((size_t)bh * SEQ + qbase + ql) * 64 + l31;
        O[base]      = f2bf(o0[reg] * rcp);
        O[base + 32] = f2bf(o1[reg] * rcp);
    }
}

// ---------------- FC + tanh: rows ordered (b, q, h) ------------------------
__global__ __launch_bounds__(256) void fc_kernel(const unsigned short* __restrict__ O,
                                                 const unsigned short* __restrict__ WfcT,
                                                 const float* __restrict__ bfc,
                                                 float* __restrict__ out) {
    int tid = threadIdx.x, w = tid >> 6, lane = tid & 63;
    int l15 = lane & 15, l4 = lane >> 4;
    int r0 = blockIdx.x * 64 + w * 16;

    int row = r0 + l15;
    int h = row & 15, t_ = row >> 4;
    int q = t_ & 2047, b = t_ >> 11;
    const unsigned short* op = O + (((size_t)(b * NH + h)) * SEQ + q) * 64 + l4 * 8;
    bf16x8 a0 = ld8(op), a1 = ld8(op + 32);

    for (int ct = 0; ct < 4; ++ct) {
        const unsigned short* wp = WfcT + (ct * 16 + l15) * 64 + l4 * 8;
        bf16x8 b0 = ld8(wp), b1 = ld8(wp + 32);
        f32x4 acc = {0.f, 0.f, 0.f, 0.f};
        acc = __builtin_amdgcn_mfma_f32_16x16x32_bf16(a0, b0, acc, 0, 0, 0);
        acc = __builtin_amdgcn_mfma_f32_16x16x32_bf16(a1, b1, acc, 0, 0, 0);
        float bias = bfc[ct * 16 + l15];
        for (int r = 0; r < 4; ++r)
            out[(size_t)(r0 + l4 * 4 + r) * 64 + ct * 16 + l15] =
                tanhf(acc[r] + bias);
    }
}

extern "C" void kernel_launch(void* const* d_in, const int* in_sizes, int n_in,
                              void* d_out, int out_size, void* d_ws, size_t ws_size,
                              hipStream_t stream) {
    const float* q_origin = (const float*)d_in[0];
    const float* k_origin = (const float*)d_in[1];
    const int*   mask     = (const int*)d_in[2];
    const float* Wq       = (const float*)d_in[3];
    const float* Wk       = (const float*)d_in[4];
    const float* Wv       = (const float*)d_in[5];
    const float* Wfc      = (const float*)d_in[6];
    const float* bfc      = (const float*)d_in[7];
    float* out = (float*)d_out;

    unsigned short* ws = (unsigned short*)d_ws;
    unsigned short* qbf  = ws;                 // dead after proj
    unsigned short* kbf  = qbf  + TOK * DH;    // dead after proj
    unsigned short* WqT  = kbf  + TOK * DH;
    unsigned short* WkT  = WqT  + 64 * PROJC;
    unsigned short* WvT  = WkT  + 64 * PROJC;
    unsigned short* WfcT = WvT  + 64 * PROJC;
    unsigned short* Qb   = WfcT + 64 * 64;
    unsigned short* Kb   = Qb   + (size_t)BSZ * NH * SEQ * DH;
    unsigned short* Vtb  = Kb   + (size_t)BSZ * NH * SEQ * DH;
    unsigned short* Ob   = Vtb  + (size_t)BSZ * NH * SEQ * DH;
    unsigned long long* mbits = (unsigned long long*)d_ws;  // aliases qbf/kbf

    prep_kernel<<<4880, 256, 0, stream>>>(q_origin, k_origin, Wq, Wk, Wv, Wfc,
                                          qbf, kbf, WqT, WkT, WvT, WfcT);
    proj_kernel<<<dim3(TOK / 64, PROJC / 64, 3), 256, 0, stream>>>(
        qbf, kbf, WqT, WkT, WvT, Qb, Kb, Vtb);
    maskpack_kernel<<<(size_t)BSZ * SEQ * SEQ / 256, 256, 0, stream>>>(mask, mbits);
    attn_kernel<<<1024, 256, 0, stream>>>(Qb, Kb, Vtb, mbits, Ob);
    fc_kernel<<<(size_t)BSZ * SEQ * NH / 64, 256, 0, stream>>>(Ob, WfcT, bfc, out);
}

// Round 9
// 183.573 us; speedup vs baseline: 3.1786x; 1.1431x over previous
//
#include <hip/hip_runtime.h>
#include <hip/hip_bf16.h>

// Problem constants
#define BSZ 4
#define SEQ 2048
#define NH  16
#define DH  64
#define TOK (BSZ*SEQ)          // 8192 tokens
#define PROJC (NH*DH)          // 1024

typedef __bf16 bf16x8 __attribute__((ext_vector_type(8)));
typedef float  f32x4  __attribute__((ext_vector_type(4)));
typedef float  f32x16 __attribute__((ext_vector_type(16)));
typedef unsigned int uint4v __attribute__((ext_vector_type(4)));
typedef unsigned int uint2v __attribute__((ext_vector_type(2)));

__device__ inline unsigned short f2bf(float f) {
    __bf16 h = (__bf16)f;
    return __builtin_bit_cast(unsigned short, h);
}

__device__ inline bf16x8 ld8(const unsigned short* p) {
    return __builtin_bit_cast(bf16x8, *reinterpret_cast<const uint4v*>(p));
}

// raw v_exp_f32 (2^x): 1 instruction, no OCML range/denorm guards.
__device__ inline float fexp2(float x) {
    float r;
    asm("v_exp_f32 %0, %1" : "=v"(r) : "v"(x));
    return r;
}

// async global -> LDS, 16B per lane; LDS dest = wave-uniform base + lane*16
__device__ inline void gload16(const unsigned short* g, unsigned short* l) {
    __builtin_amdgcn_global_load_lds(
        (__attribute__((address_space(1))) void*)g,
        (__attribute__((address_space(3))) void*)l, 16, 0, 0);
}

// ---------------- fused prep: conv (f32->bf16) + 4x weight transpose -------
__global__ __launch_bounds__(256) void prep_kernel(const float* __restrict__ q,
                                                   const float* __restrict__ k,
                                                   const float* __restrict__ Wq,
                                                   const float* __restrict__ Wk,
                                                   const float* __restrict__ Wv,
                                                   const float* __restrict__ Wfc,
                                                   unsigned short* __restrict__ qbf,
                                                   unsigned short* __restrict__ kbf,
                                                   unsigned short* __restrict__ WqT,
                                                   unsigned short* __restrict__ WkT,
                                                   unsigned short* __restrict__ WvT,
                                                   unsigned short* __restrict__ WfcT) {
    int bx = blockIdx.x;
    if (bx < 4096) {
        int idx = (bx & 2047) * 256 + threadIdx.x;
        if (bx < 2048) qbf[idx] = f2bf(q[idx]);
        else           kbf[idx] = f2bf(k[idx]);
        return;
    }
    bx -= 4096;
    const float* W; unsigned short* WT; int cols; int base;
    if      (bx < 256) { W = Wq;  WT = WqT;  cols = PROJC; base = bx; }
    else if (bx < 512) { W = Wk;  WT = WkT;  cols = PROJC; base = bx - 256; }
    else if (bx < 768) { W = Wv;  WT = WvT;  cols = PROJC; base = bx - 512; }
    else               { W = Wfc; WT = WfcT; cols = 64;    base = bx - 768; }
    int idx = base * 256 + threadIdx.x;
    int c = idx % cols, kk = idx / cols;
    WT[c * 64 + kk] = f2bf(W[kk * cols + c]);
}

// ---------------- mask bit-pack: int32 [b][q][k] -> uint64 bitrows ---------
__global__ __launch_bounds__(256) void maskpack_kernel(const int* __restrict__ mask,
                                                       unsigned long long* __restrict__ mbits) {
    size_t gid = (size_t)blockIdx.x * 256 + threadIdx.x;
    int lane = threadIdx.x & 63;
    unsigned long long bal = __ballot(mask[gid] != 0);
    if (lane == 0) mbits[gid >> 6] = bal;
}

// ---------------- projections: tokens x 64 @ 64 x 1024 ---------------------
__global__ __launch_bounds__(256) void proj_kernel(const unsigned short* __restrict__ qbf,
                                                   const unsigned short* __restrict__ kbf,
                                                   const unsigned short* __restrict__ WqT,
                                                   const unsigned short* __restrict__ WkT,
                                                   const unsigned short* __restrict__ WvT,
                                                   unsigned short* __restrict__ Qo,
                                                   unsigned short* __restrict__ Ko,
                                                   unsigned short* __restrict__ Vto) {
    int z = blockIdx.z;
    const unsigned short* A  = (z == 0) ? qbf : kbf;
    const unsigned short* WT = (z == 0) ? WqT : (z == 1) ? WkT : WvT;
    int tid = threadIdx.x, w = tid >> 6, lane = tid & 63;
    int l15 = lane & 15, l4 = lane >> 4;
    int r0 = blockIdx.x * 64 + w * 16;
    int c0 = blockIdx.y * 64;
    int h = blockIdx.y;
    int b = r0 >> 11;
    size_t bh = (size_t)(b * NH + h);

    const unsigned short* ap = A + (r0 + l15) * 64 + l4 * 8;
    bf16x8 a0 = ld8(ap), a1 = ld8(ap + 32);

    for (int ct = 0; ct < 4; ++ct) {
        const unsigned short* wp = WT + (c0 + ct * 16 + l15) * 64 + l4 * 8;
        bf16x8 b0 = ld8(wp), b1 = ld8(wp + 32);
        f32x4 acc = {0.f, 0.f, 0.f, 0.f};
        if (z == 2) {
            acc = __builtin_amdgcn_mfma_f32_16x16x32_bf16(a0, b0, acc, 0, 0, 0);
            acc = __builtin_amdgcn_mfma_f32_16x16x32_bf16(a1, b1, acc, 0, 0, 0);
        } else {
            acc = __builtin_amdgcn_mfma_f32_16x16x32_bf16(b0, a0, acc, 0, 0, 0);
            acc = __builtin_amdgcn_mfma_f32_16x16x32_bf16(b1, a1, acc, 0, 0, 0);
        }
        uint2v pk;
        pk.x = (unsigned)f2bf(acc[0]) | ((unsigned)f2bf(acc[1]) << 16);
        pk.y = (unsigned)f2bf(acc[2]) | ((unsigned)f2bf(acc[3]) << 16);
        if (z == 2) {
            int dd = ct * 16 + l15;
            int q0 = (r0 + l4 * 4) & 2047;
            *reinterpret_cast<uint2v*>(Vto + (bh * 64 + dd) * SEQ + q0) = pk;
        } else {
            int qq = (r0 + l15) & 2047;
            unsigned short* dst = (z == 0) ? Qo : Ko;
            *reinterpret_cast<uint2v*>(dst + (bh * SEQ + qq) * 64 + ct * 16 + l4 * 4) = pk;
        }
    }
}

// ---------------- flash attention: 32x32 MFMA, P fully in-register ---------
// Grid 1024 (XCD-swizzled), 256 threads = 4 waves, 32 q rows per wave.
// K/V tiles [64][64] double-buffered in LDS via global_load_lds (linear dest,
// XOR-16B-swizzled source; reads apply the same XOR). Swapped QK^T: lane
// (q=lane&31, hi) holds S[q][k=(reg&3)+8*(reg>>2)+4*hi]. PV k-slices chosen
// as the union of the two half-wave k-sets, so the PV A-frag is the lane's
// own 4 packed words (no cross-lane, no P LDS). ell via ones-MFMA lands in
// O's D-layout. Static max m=0; fully-masked rows -> ell==0 -> 0.
// Softmax uses raw v_exp_f32 (exp2(-inf)=0 keeps mask semantics exact).
__global__ __launch_bounds__(256, 4) void attn_kernel(const unsigned short* __restrict__ Q,
                                                      const unsigned short* __restrict__ K,
                                                      const unsigned short* __restrict__ Vt,
                                                      const unsigned long long* __restrict__ mbits,
                                                      unsigned short* __restrict__ O) {
    __shared__ __align__(16) unsigned short Ks[2][64 * 64];   // 16 KB
    __shared__ __align__(16) unsigned short Vs[2][64 * 64];   // 16 KB
    int tid = threadIdx.x, w = tid >> 6, lane = tid & 63;
    int l31 = lane & 31, hi = lane >> 5;
    int hi4 = hi * 4;

    // XCD-aware swizzle: 1024 % 8 == 0, bijective
    int bid = blockIdx.x;
    int swz = (bid & 7) * 128 + (bid >> 3);
    int bh = swz >> 4;              // 0..63
    int qt = swz & 15;              // 0..15
    int b = bh >> 4;
    int qbase = qt * 128 + w * 32;

    const unsigned short* Qh = Q  + (size_t)bh * SEQ * 64;
    const unsigned short* Kh = K  + (size_t)bh * SEQ * 64;
    const unsigned short* Vh = Vt + (size_t)bh * 64 * SEQ;
    const unsigned long long* mrow =
        mbits + ((size_t)b * SEQ + qbase + l31) * (SEQ / 64);

    // staging geometry: chunk idx = w*64 + lane (+256), row = idx>>3, col16 = idx&7
    int row1 = (w << 3) + (lane >> 3);          // 0..31
    int row2 = row1 + 32;
    int sc1 = (lane & 7) ^ (row1 & 7);          // source chunk (XOR involution)
    unsigned short* Kd0 = &Ks[0][0] + w * 512;
    unsigned short* Vd0 = &Vs[0][0] + w * 512;
    unsigned short* Kd1 = &Ks[1][0] + w * 512;
    unsigned short* Vd1 = &Vs[1][0] + w * 512;

    // Q B-frags: lane holds Q[qbase+l31][s*16 + hi*8 + j]
    bf16x8 qf[4];
    #pragma unroll
    for (int s = 0; s < 4; ++s)
        qf[s] = ld8(Qh + (size_t)(qbase + l31) * 64 + s * 16 + hi * 8);

    bf16x8 ones;
    #pragma unroll
    for (int i = 0; i < 8; ++i) ones[i] = (__bf16)1.0f;

    f32x16 o0 = {0.f,0.f,0.f,0.f,0.f,0.f,0.f,0.f,0.f,0.f,0.f,0.f,0.f,0.f,0.f,0.f};
    f32x16 o1 = o0;
    f32x16 ellD = o0;
    const float C = 0.125f * 1.44269504088896f;   // scale * log2(e)

    // prologue: stage kb=0 into buffer 0
    gload16(Kh + (size_t)row1 * 64 + sc1 * 8, Kd0);
    gload16(Kh + (size_t)row2 * 64 + sc1 * 8, Kd0 + 2048);
    gload16(Vh + (size_t)row1 * SEQ + sc1 * 8, Vd0);
    gload16(Vh + (size_t)row2 * SEQ + sc1 * 8, Vd0 + 2048);
    __syncthreads();

    int cur = 0;
    for (int kb = 0; kb < SEQ; kb += 64) {
        // ---- stage next tile (async DMA, in flight across compute)
        if (kb + 64 < SEQ) {
            int nkb = kb + 64;
            unsigned short* Kd = cur ? Kd0 : Kd1;
            unsigned short* Vd = cur ? Vd0 : Vd1;
            gload16(Kh + (size_t)(nkb + row1) * 64 + sc1 * 8, Kd);
            gload16(Kh + (size_t)(nkb + row2) * 64 + sc1 * 8, Kd + 2048);
            gload16(Vh + (size_t)row1 * SEQ + nkb + sc1 * 8, Vd);
            gload16(Vh + (size_t)row2 * SEQ + nkb + sc1 * 8, Vd + 2048);
        }
        unsigned long long wb = mrow[kb >> 6];
        const unsigned short* Kc = &Ks[cur][0];
        const unsigned short* Vc = &Vs[cur][0];

        #pragma unroll
        for (int kt = 0; kt < 2; ++kt) {
            // ---- QK^T (swapped): z[reg] = S[q=l31][k=kt*32+(reg&3)+8*(reg>>2)+4hi]
            f32x16 z = {0.f,0.f,0.f,0.f,0.f,0.f,0.f,0.f,0.f,0.f,0.f,0.f,0.f,0.f,0.f,0.f};
            int krow = kt * 32 + l31;
            #pragma unroll
            for (int s = 0; s < 4; ++s) {
                const unsigned short* kp =
                    Kc + krow * 64 + ((((s << 1) + hi) ^ (krow & 7)) << 3);
                z = __builtin_amdgcn_mfma_f32_32x32x16_bf16(ld8(kp), qf[s], z, 0, 0, 0);
            }
            // ---- mask (0/-inf bias via bfe) + v_exp_f32 + pack to bf16 pairs
            unsigned wsh = (unsigned)(wb >> (kt * 32)) >> hi4;  // lane's bits at 0..27
            unsigned wpk[8];
            #pragma unroll
            for (int rq = 0; rq < 4; ++rq) {
                #pragma unroll
                for (int rr = 0; rr < 2; ++rr) {
                    float e[2];
                    #pragma unroll
                    for (int j = 0; j < 2; ++j) {
                        int pos = rq * 8 + 2 * rr + j;          // compile-time
                        int sx = (int)(wsh << (31 - pos)) >> 31; // v_bfe_i32
                        float bias = __builtin_bit_cast(float, (unsigned)sx & 0xFF800000u);
                        e[j] = fexp2(__builtin_fmaf(z[rq * 4 + 2 * rr + j], C, bias));
                    }
                    wpk[rq * 2 + rr] = (unsigned)f2bf(e[0]) | ((unsigned)f2bf(e[1]) << 16);
                }
            }
            // ---- ell + PV: A-frag = own words (k-subset trick), V matches
            __builtin_amdgcn_s_setprio(1);
            #pragma unroll
            for (int sl = 0; sl < 2; ++sl) {
                uint4v aw = {wpk[sl * 4 + 0], wpk[sl * 4 + 1],
                             wpk[sl * 4 + 2], wpk[sl * 4 + 3]};
                bf16x8 af = __builtin_bit_cast(bf16x8, aw);
                ellD = __builtin_amdgcn_mfma_f32_32x32x16_bf16(af, ones, ellD, 0, 0, 0);
                int n = kt * 2 + sl;            // k-subtile of 16 within kb
                {   // dtile 0
                    int vrow = l31;
                    int c0i = ((2 * n) ^ (vrow & 7)) << 3;
                    int c1i = ((2 * n + 1) ^ (vrow & 7)) << 3;
                    uint2v lo = *reinterpret_cast<const uint2v*>(Vc + vrow * 64 + c0i + hi4);
                    uint2v hh = *reinterpret_cast<const uint2v*>(Vc + vrow * 64 + c1i + hi4);
                    uint4v vw = {lo.x, lo.y, hh.x, hh.y};
                    o0 = __builtin_amdgcn_mfma_f32_32x32x16_bf16(
                        af, __builtin_bit_cast(bf16x8, vw), o0, 0, 0, 0);
                }
                {   // dtile 1
                    int vrow = 32 + l31;
                    int c0i = ((2 * n) ^ (vrow & 7)) << 3;
                    int c1i = ((2 * n + 1) ^ (vrow & 7)) << 3;
                    uint2v lo = *reinterpret_cast<const uint2v*>(Vc + vrow * 64 + c0i + hi4);
                    uint2v hh = *reinterpret_cast<const uint2v*>(Vc + vrow * 64 + c1i + hi4);
                    uint4v vw = {lo.x, lo.y, hh.x, hh.y};
                    o1 = __builtin_amdgcn_mfma_f32_32x32x16_bf16(
                        af, __builtin_bit_cast(bf16x8, vw), o1, 0, 0, 0);
                }
            }
            __builtin_amdgcn_s_setprio(0);
        }
        __syncthreads();
        cur ^= 1;
    }
    // ---- normalize + store; lane holds O[q=(reg&3)+8*(reg>>2)+4hi][d=dt*32+l31]
    #pragma unroll
    for (int reg = 0; reg < 16; ++reg) {
        float l = ellD[reg];
        float rcp = (l == 0.f) ? 0.f : __builtin_amdgcn_rcpf(l);
        int ql = (reg & 3) + 8 * (reg >> 2) + hi4;
        size_t base = ((size_t)bh * SEQ + qbase + ql) * 64 + l31;
        O[base]      = f2bf(o0[reg] * rcp);
        O[base + 32] = f2bf(o1[reg] * rcp);
    }
}

// ---------------- FC + tanh: rows ordered (b, q, h) ------------------------
// tanh(x) = (t-1)/(t+1), t = exp2(2*log2e*x), x clamped to +-9 (err ~1e-7).
__global__ __launch_bounds__(256) void fc_kernel(const unsigned short* __restrict__ O,
                                                 const unsigned short* __restrict__ WfcT,
                                                 const float* __restrict__ bfc,
                                                 float* __restrict__ out) {
    int tid = threadIdx.x, w = tid >> 6, lane = tid & 63;
    int l15 = lane & 15, l4 = lane >> 4;
    int r0 = blockIdx.x * 64 + w * 16;

    int row = r0 + l15;
    int h = row & 15, t_ = row >> 4;
    int q = t_ & 2047, b = t_ >> 11;
    const unsigned short* op = O + (((size_t)(b * NH + h)) * SEQ + q) * 64 + l4 * 8;
    bf16x8 a0 = ld8(op), a1 = ld8(op + 32);

    for (int ct = 0; ct < 4; ++ct) {
        const unsigned short* wp = WfcT + (ct * 16 + l15) * 64 + l4 * 8;
        bf16x8 b0 = ld8(wp), b1 = ld8(wp + 32);
        f32x4 acc = {0.f, 0.f, 0.f, 0.f};
        acc = __builtin_amdgcn_mfma_f32_16x16x32_bf16(a0, b0, acc, 0, 0, 0);
        acc = __builtin_amdgcn_mfma_f32_16x16x32_bf16(a1, b1, acc, 0, 0, 0);
        float bias = bfc[ct * 16 + l15];
        for (int r = 0; r < 4; ++r) {
            float x = acc[r] + bias;
            x = fminf(fmaxf(x, -9.f), 9.f);
            float t = fexp2(x * 2.88539008177793f);     // 2*log2(e)
            float res = (t - 1.f) * __builtin_amdgcn_rcpf(t + 1.f);
            out[(size_t)(r0 + l4 * 4 + r) * 64 + ct * 16 + l15] = res;
        }
    }
}

extern "C" void kernel_launch(void* const* d_in, const int* in_sizes, int n_in,
                              void* d_out, int out_size, void* d_ws, size_t ws_size,
                              hipStream_t stream) {
    const float* q_origin = (const float*)d_in[0];
    const float* k_origin = (const float*)d_in[1];
    const int*   mask     = (const int*)d_in[2];
    const float* Wq       = (const float*)d_in[3];
    const float* Wk       = (const float*)d_in[4];
    const float* Wv       = (const float*)d_in[5];
    const float* Wfc      = (const float*)d_in[6];
    const float* bfc      = (const float*)d_in[7];
    float* out = (float*)d_out;

    unsigned short* ws = (unsigned short*)d_ws;
    unsigned short* qbf  = ws;                 // dead after proj
    unsigned short* kbf  = qbf  + TOK * DH;    // dead after proj
    unsigned short* WqT  = kbf  + TOK * DH;
    unsigned short* WkT  = WqT  + 64 * PROJC;
    unsigned short* WvT  = WkT  + 64 * PROJC;
    unsigned short* WfcT = WvT  + 64 * PROJC;
    unsigned short* Qb   = WfcT + 64 * 64;
    unsigned short* Kb   = Qb   + (size_t)BSZ * NH * SEQ * DH;
    unsigned short* Vtb  = Kb   + (size_t)BSZ * NH * SEQ * DH;
    unsigned short* Ob   = Vtb  + (size_t)BSZ * NH * SEQ * DH;
    unsigned long long* mbits = (unsigned long long*)d_ws;  // aliases qbf/kbf

    prep_kernel<<<4880, 256, 0, stream>>>(q_origin, k_origin, Wq, Wk, Wv, Wfc,
                                          qbf, kbf, WqT, WkT, WvT, WfcT);
    proj_kernel<<<dim3(TOK / 64, PROJC / 64, 3), 256, 0, stream>>>(
        qbf, kbf, WqT, WkT, WvT, Qb, Kb, Vtb);
    maskpack_kernel<<<(size_t)BSZ * SEQ * SEQ / 256, 256, 0, stream>>>(mask, mbits);
    attn_kernel<<<1024, 256, 0, stream>>>(Qb, Kb, Vtb, mbits, Ob);
    fc_kernel<<<(size_t)BSZ * SEQ * NH / 64, 256, 0, stream>>>(Ob, WfcT, bfc, out);
}